// Round 6
// baseline (585.415 us; speedup 1.0000x reference)
//
#include <hip/hip_runtime.h>
#include <stdint.h>

#define IN_F 4096
#define OUT_F 14336
#define QBLK 64

__device__ __constant__ float NF4_CODE_C[16] = {
    -1.0f, -0.6961928009986877f, -0.5250730514526367f, -0.39491748809814453f,
    -0.28444138169288635f, -0.18477343022823334f, -0.09105003625154495f, 0.0f,
    0.07958029955625534f, 0.16093020141124725f, 0.24611230194568634f,
    0.33791524171829224f, 0.44070982933044434f, 0.5626170039176941f,
    0.8333911895751953f, 1.0f};

typedef __attribute__((ext_vector_type(8))) short short8;   // 8 bf16 (4 VGPRs)
typedef __attribute__((ext_vector_type(4))) float f32x4;    // MFMA acc

__device__ __forceinline__ unsigned short f32_to_bf16_rne(float f) {
    union { float f; uint32_t u; } a; a.f = f;
    uint32_t u = a.u;
    uint32_t r = u + 0x7fffu + ((u >> 16) & 1u);
    return (unsigned short)(r >> 16);
}

// ---------------- Pass 1a: dequant W -> bf16 [N][K]
__global__ void dequant_w_kernel(const int* __restrict__ w,
                                 const float* __restrict__ absmax,
                                 unsigned short* __restrict__ W,
                                 long long n8) {
    long long i = (long long)blockIdx.x * blockDim.x + threadIdx.x;
    long long stride = (long long)gridDim.x * blockDim.x;
    for (; i < n8; i += stride) {
        const int4* p = (const int4*)(w + i * 8);
        int4 v0 = p[0], v1 = p[1];
        float s = absmax[i >> 3];
        union { unsigned short u[8]; float4 v; } out;
        out.u[0] = f32_to_bf16_rne(NF4_CODE_C[v0.x] * s);
        out.u[1] = f32_to_bf16_rne(NF4_CODE_C[v0.y] * s);
        out.u[2] = f32_to_bf16_rne(NF4_CODE_C[v0.z] * s);
        out.u[3] = f32_to_bf16_rne(NF4_CODE_C[v0.w] * s);
        out.u[4] = f32_to_bf16_rne(NF4_CODE_C[v1.x] * s);
        out.u[5] = f32_to_bf16_rne(NF4_CODE_C[v1.y] * s);
        out.u[6] = f32_to_bf16_rne(NF4_CODE_C[v1.z] * s);
        out.u[7] = f32_to_bf16_rne(NF4_CODE_C[v1.w] * s);
        *(float4*)(W + i * 8) = out.v;
    }
}

// ---------------- Pass 1b: x fp32 -> bf16
__global__ void cvt_x_kernel(const float* __restrict__ x,
                             unsigned short* __restrict__ xb,
                             long long n8) {
    long long i = (long long)blockIdx.x * blockDim.x + threadIdx.x;
    long long stride = (long long)gridDim.x * blockDim.x;
    for (; i < n8; i += stride) {
        const float4* p = (const float4*)(x + i * 8);
        float4 a = p[0], b = p[1];
        union { unsigned short u[8]; float4 v; } out;
        out.u[0] = f32_to_bf16_rne(a.x);
        out.u[1] = f32_to_bf16_rne(a.y);
        out.u[2] = f32_to_bf16_rne(a.z);
        out.u[3] = f32_to_bf16_rne(a.w);
        out.u[4] = f32_to_bf16_rne(b.x);
        out.u[5] = f32_to_bf16_rne(b.y);
        out.u[6] = f32_to_bf16_rne(b.z);
        out.u[7] = f32_to_bf16_rne(b.w);
        *(float4*)(xb + i * 8) = out.v;
    }
}

// ---------------- Pass 2: 128x256-tile pipelined bf16 GEMM (B^T)
// 1792 blocks = 7/CU exact (no tail idle). 8 waves (2M x 4N), wave tile 64x64,
// BK=64, 3 LDS buffers (144 KiB), 2-tile-ahead prefetch, vmcnt(6) ONCE per
// K-tile (r4-proven single-barrier phases; m201-style counted discipline).
// Ledger: tile t+1's 6 loads issued during t-1; VMW(6) at t's ph4 leaves only
// t+2's 6 outstanding => t+1 fully landed before its reads. WAR on buffers is
// separated by >=2 barriers (reads consumed by MFMA before ph4 BAR; writes
// issued after next ph1 BAR).
__device__ __forceinline__ void llds16(const unsigned short* g, unsigned short* l) {
    __builtin_amdgcn_global_load_lds(
        (const __attribute__((address_space(1))) unsigned int*)g,
        (__attribute__((address_space(3))) unsigned int*)l,
        16, 0, 0);
}

#define GK 4096
#define GN 14336

__global__ void __launch_bounds__(512, 2)
gemm_3buf_bf16(const unsigned short* __restrict__ A,  // [M][4096] bf16 bits
               const unsigned short* __restrict__ B,  // [14336][4096] bf16 bits
               const float* __restrict__ bias,
               float* __restrict__ C, int Mtiles) {
    // 3 buffers x (A 128x64 + B 256x64) bf16 = 3 x 48 KB = 144 KiB
    __shared__ unsigned short lds[73728];
    const int tid  = threadIdx.x;
    const int lane = tid & 63;
    const int wv   = tid >> 6;        // wave 0..7
    const int wr   = wv >> 2;         // M half (0..1) -> rows wr*64
    const int wc   = wv & 3;          // N quarter     -> cols wc*64
    const int l7   = lane & 7;

    // T1: bijective XCD swizzle (m204); tm-fast within chunk (B-panel L2 reuse)
    const int nwg = gridDim.x;
    const int q = nwg >> 3, r = nwg & 7;
    const int xcd = blockIdx.x & 7, loc = blockIdx.x >> 3;
    const int s = (xcd < r ? xcd * (q + 1) : r * (q + 1) + (xcd - r) * q) + loc;
    const int tm = s % Mtiles;
    const int tn = s / Mtiles;
    const int brow = tm * 128;
    const int bcol = tn * 256;

    f32x4 acc[4][4] = {};

    // staging: thread t -> row t>>3 (0..63 per chunk), LDS slot t&7 linear,
    // global 16B-chunk pre-swizzled: gch = (t&7) ^ ((t>>3)&7)  [T2, rule #21]
    const int srow = tid >> 3;
    const int gch  = ((tid & 7) ^ ((tid >> 3) & 7)) * 8;
    const unsigned short* pA = A + (size_t)(brow + srow) * GK + gch;
    const unsigned short* pB = B + (size_t)(bcol + srow) * GK + gch;

    // read offsets: elem (row,kslot s) at row*64 + (s ^ (row&7))*8
    const int sl0 = (((lane >> 4)    ) ^ l7) * 8;
    const int sl1 = (((lane >> 4) + 4) ^ l7) * 8;
    const int aoff = (wr * 64 + (lane & 15)) * 64;           // + i*1024
    const int boff = 8192 + (wc * 64 + (lane & 15)) * 64;    // + n*1024

#define O0 0
#define O1 24576
#define O2 49152

#define ST_A(c, T, S) llds16(pA + (size_t)(c) * 64 * GK + (size_t)(T) * 64, \
                             &lds[(S) + (c) * 4096 + wv * 512])
#define ST_B(c, T, S) llds16(pB + (size_t)(c) * 64 * GK + (size_t)(T) * 64, \
                             &lds[(S) + 8192 + (c) * 4096 + wv * 512])

#define RD_AF(i, O) do { \
    af[i][0] = *(const short8*)&lds[(O) + aoff + (i) * 1024 + sl0]; \
    af[i][1] = *(const short8*)&lds[(O) + aoff + (i) * 1024 + sl1]; } while (0)
#define RD_BQ(n, O) do { \
    bq[n][0] = *(const short8*)&lds[(O) + boff + (n) * 1024 + sl0]; \
    bq[n][1] = *(const short8*)&lds[(O) + boff + (n) * 1024 + sl1]; } while (0)

#define MMQ(qm, qn) do { __builtin_amdgcn_s_setprio(1); \
    _Pragma("unroll") for (int i2 = 0; i2 < 2; ++i2) \
    _Pragma("unroll") for (int n2 = 0; n2 < 2; ++n2) \
    _Pragma("unroll") for (int kk = 0; kk < 2; ++kk) \
        acc[(qm)*2+i2][(qn)*2+n2] = __builtin_amdgcn_mfma_f32_16x16x32_bf16( \
            af[(qm)*2+i2][kk], bq[(qn)*2+n2][kk], acc[(qm)*2+i2][(qn)*2+n2], 0, 0, 0); \
    __builtin_amdgcn_s_setprio(0); } while (0)

#define VMW(N) asm volatile("s_waitcnt vmcnt(" #N ")" ::: "memory")
#define BAR()  __builtin_amdgcn_s_barrier()

// compute buffer O, stage K-tile T into buffer S (4 phases, r4 shape)
#define TILE_BODY(O, S, T) do { \
    short8 af[4][2], bq[4][2]; \
    BAR(); ST_A(0, T, S); ST_A(1, T, S); \
    RD_AF(0, O); RD_AF(1, O); RD_BQ(0, O); RD_BQ(1, O); \
    MMQ(0, 0); \
    BAR(); ST_B(0, T, S); ST_B(1, T, S); \
    RD_BQ(2, O); RD_BQ(3, O); \
    MMQ(0, 1); \
    BAR(); ST_B(2, T, S); ST_B(3, T, S); \
    RD_AF(2, O); RD_AF(3, O); \
    MMQ(1, 0); \
    VMW(6); BAR(); \
    MMQ(1, 1); \
} while (0)

#define TILE_NOSTAGE(O) do { \
    short8 af[4][2], bq[4][2]; \
    RD_AF(0, O); RD_AF(1, O); RD_BQ(0, O); RD_BQ(1, O); MMQ(0, 0); \
    RD_BQ(2, O); RD_BQ(3, O); MMQ(0, 1); \
    RD_AF(2, O); RD_AF(3, O); MMQ(1, 0); MMQ(1, 1); \
} while (0)

    // prologue: stage tiles 0 -> buf0, 1 -> buf1; land tile 0 (first 6)
    ST_A(0, 0, O0); ST_A(1, 0, O0);
    ST_B(0, 0, O0); ST_B(1, 0, O0); ST_B(2, 0, O0); ST_B(3, 0, O0);
    ST_A(0, 1, O1); ST_A(1, 1, O1);
    ST_B(0, 1, O1); ST_B(1, 1, O1); ST_B(2, 1, O1); ST_B(3, 1, O1);
    VMW(6);

    // main: 64 K-tiles; t = 0..59 in 20 triple-iterations (tile t stages t+2)
    #pragma unroll 1
    for (int t = 0; t < 60; t += 3) {
        TILE_BODY(O0, O2, t + 2);
        TILE_BODY(O1, O0, t + 3);
        TILE_BODY(O2, O1, t + 4);
    }
    TILE_BODY(O0, O2, 62);          // t=60
    TILE_BODY(O1, O0, 63);          // t=61
    BAR(); TILE_NOSTAGE(O2);        // t=62
    VMW(0); BAR();
    TILE_NOSTAGE(O0);               // t=63

#undef TILE_BODY
#undef TILE_NOSTAGE
#undef VMW
#undef BAR
#undef MMQ
#undef RD_AF
#undef RD_BQ
#undef ST_A
#undef ST_B
#undef O0
#undef O1
#undef O2

    // epilogue: D col = lane&15, row = (lane>>4)*4 + j  [verified layout]
    #pragma unroll
    for (int n = 0; n < 4; ++n) {
        const int col = bcol + wc * 64 + n * 16 + (lane & 15);
        const float bv = bias[col];
        #pragma unroll
        for (int i = 0; i < 4; ++i) {
            #pragma unroll
            for (int j = 0; j < 4; ++j) {
                const int row = brow + wr * 64 + i * 16 + (lane >> 4) * 4 + j;
                C[(size_t)row * GN + col] = acc[i][n][j] + bv;
            }
        }
    }
}

// ---------------- fallback: naive fused fp32
__global__ void naive_fused(const float* __restrict__ x, const int* __restrict__ w,
                            const float* __restrict__ am, const float* __restrict__ bias,
                            float* __restrict__ out, int M) {
    long long o = (long long)blockIdx.x * blockDim.x + threadIdx.x;
    if (o >= (long long)M * OUT_F) return;
    int m = (int)(o / OUT_F), n = (int)(o % OUT_F);
    const int* wr_ = w + (size_t)n * IN_F;
    const float* xr = x + (size_t)m * IN_F;
    const float* amr = am + (size_t)n * (IN_F / QBLK);
    float sum = 0.f;
    for (int k = 0; k < IN_F; ++k)
        sum += xr[k] * NF4_CODE_C[wr_[k]] * amr[k >> 6];
    out[o] = sum + bias[n];
}

extern "C" void kernel_launch(void* const* d_in, const int* in_sizes, int n_in,
                              void* d_out, int out_size, void* d_ws, size_t ws_size,
                              hipStream_t stream) {
    const float* x      = (const float*)d_in[0];
    const int*   w_idx  = (const int*)d_in[1];
    const float* absmax = (const float*)d_in[2];
    const float* bias   = (const float*)d_in[3];
    float* out = (float*)d_out;

    const int M = in_sizes[0] / IN_F;   // 4096
    const int N = OUT_F;                // 14336
    const int K = IN_F;                 // 4096

    const size_t needW = (size_t)N * K * 2;
    const size_t needX = (size_t)M * K * 2;
    if (ws_size >= needW + needX && (M % 128) == 0) {
        unsigned short* Wb = (unsigned short*)d_ws;
        unsigned short* Xb = (unsigned short*)((char*)d_ws + needW);

        long long n8w = (long long)N * K / 8;
        dequant_w_kernel<<<8192, 256, 0, stream>>>(w_idx, absmax, Wb, n8w);
        long long n8x = (long long)M * K / 8;
        cvt_x_kernel<<<4096, 256, 0, stream>>>(x, Xb, n8x);

        const int Mtiles = M / 128;
        dim3 grid(Mtiles * (N / 256));
        gemm_3buf_bf16<<<grid, 512, 0, stream>>>(Xb, Wb, bias, out, Mtiles);
    } else {
        long long total = (long long)M * OUT_F;
        int blocks = (int)((total + 255) / 256);
        naive_fused<<<blocks, 256, 0, stream>>>(x, w_idx, absmax, bias, out, M);
    }
}